// Round 2
// 656.628 us; speedup vs baseline: 1.0284x; 1.0284x over previous
//
#include <hip/hip_runtime.h>

// MetaLayer GNN on MI355X — round 3 resubmit (round-1 bench was an infra
// failure: "container failed twice", no compile/test evidence against this
// source). Weight fragments in registers: the MFMA B-operand depends only on
// (wave, lane, type), so each thread loads its own weight fragment straight
// from global f32 (L2-hot, 3 tiny matrices) instead of every block
// transposing 48 KB of weights into LDS with scalar 8-way-bank-conflicted
// ds_write_b16s. LDS shrinks 48KB -> ~22KB, raising occupancy from 3 to ~4
// blocks/CU. fp32 atomic scatter kept unchanged as the diagnostic control.

constexpr int NA = 100000;
constexpr int NEDGE = 400000;
constexpr int DN = 64;
constexpr int DE = 32;
constexpr int DH = 64;

constexpr int WS_SUM = NA * DE;           // 3.2M floats per sum buffer
constexpr int WS_FLOATS = 4 * WS_SUM + 4 * NA;

constexpr int FSTR = 168;  // edge concat-feature stride (160 + 8 pad)
constexpr int NSTR = 136;  // node concat-feature stride (128 + 8 pad)
constexpr int HSTR = 72;   // hidden stride (64 + 8 pad)

typedef __bf16 bf16x8 __attribute__((ext_vector_type(8)));
typedef __bf16 bf16x4 __attribute__((ext_vector_type(4)));
typedef float f32x4 __attribute__((ext_vector_type(4)));

__global__ __launch_bounds__(256) void zero_ws(float4* __restrict__ ws, int n4) {
    int i = blockIdx.x * 256 + threadIdx.x;
    int stride = gridDim.x * 256;
    for (; i < n4; i += stride) ws[i] = make_float4(0.f, 0.f, 0.f, 0.f);
}

// ---------------- edge kernel ----------------
__global__ __launch_bounds__(256, 4) void edge_kernel(
    const float* __restrict__ x_a, const float* __restrict__ x_b,
    const int* __restrict__ ei_aa, const int* __restrict__ ei_ab, const int* __restrict__ ei_bb,
    const float* __restrict__ ea_aa, const float* __restrict__ ea_ab, const float* __restrict__ ea_bb,
    const float* __restrict__ We1, const float* __restrict__ be1,
    const float* __restrict__ We2, const float* __restrict__ be2,
    float* __restrict__ ne_out,   // 3 ne arrays back-to-back, [3*NEDGE][32]
    float* __restrict__ ws)
{
    __shared__ __bf16 feat[64 * FSTR];   // concat features, [64 edges][160]
    __shared__ int sidx[64], didx[64];

    const int tid = threadIdx.x;
    constexpr int BPT = NEDGE / 64;      // 6250 blocks per edge type
    const int k   = blockIdx.x / BPT;    // edge type (block-uniform)
    const int blk = blockIdx.x % BPT;

    const int*   ei = (k == 0) ? ei_aa : (k == 1) ? ei_ab : ei_bb;
    const float* ea = (k == 0) ? ea_aa : (k == 1) ? ea_ab : ea_bb;
    const float* x1 = (k == 2) ? x_b : x_a;
    const float* x2 = (k == 0) ? x_a : x_b;
    const float* __restrict__ W1 = We1 + (size_t)k * (2 * DN + DE) * DH;
    const float* __restrict__ W2 = We2 + (size_t)k * DH * DE;

    const int w = tid >> 6, lane = tid & 63;
    const int m16 = lane & 15, quad = lane >> 4;

    // ---- layer-1 B fragments: straight global->register (L2-hot weights) ----
    // b1f[kk][j] = W1[kk*32 + quad*8 + j][w*16 + m16]
    bf16x8 b1f[5];
    {
        const float* wp = W1 + (size_t)(quad * 8) * DH + (w * 16 + m16);
#pragma unroll
        for (int kk = 0; kk < 5; kk++)
#pragma unroll
            for (int j = 0; j < 8; j++)
                b1f[kk][j] = (__bf16)wp[(kk * 32 + j) * DH];
    }

    // ---- gather + convert concat features: 4 threads per edge ----
    {
        const int q = tid & 3, el = tid >> 2;
        const int e = blk * 64 + el;
        const int src = ei[e];
        const int dst = ei[NEDGE + e];
        if (q == 0) { sidx[el] = src; didx[el] = dst; }

        const float4* p1 = (const float4*)(x1 + (size_t)src * DN);
        const float4* p2 = (const float4*)(x2 + (size_t)dst * DN);
        const float4* pe = (const float4*)(ea + (size_t)e * DE);
#pragma unroll
        for (int i = 0; i < 4; i++) {
            float4 v = p1[q * 4 + i];
            bf16x4 t = {(__bf16)v.x, (__bf16)v.y, (__bf16)v.z, (__bf16)v.w};
            *(bf16x4*)&feat[el * FSTR + q * 16 + i * 4] = t;
        }
#pragma unroll
        for (int i = 0; i < 4; i++) {
            float4 v = p2[q * 4 + i];
            bf16x4 t = {(__bf16)v.x, (__bf16)v.y, (__bf16)v.z, (__bf16)v.w};
            *(bf16x4*)&feat[el * FSTR + 64 + q * 16 + i * 4] = t;
        }
#pragma unroll
        for (int i = 0; i < 2; i++) {
            float4 v = pe[q * 2 + i];
            bf16x4 t = {(__bf16)v.x, (__bf16)v.y, (__bf16)v.z, (__bf16)v.w};
            *(bf16x4*)&feat[el * FSTR + 128 + q * 8 + i * 4] = t;
        }
        // degree counts (one per edge-target)
        if (q == 0) {
            float* cnt = ws + (size_t)4 * WS_SUM;
            if (k == 0)      atomicAdd(cnt + src, 1.0f);
            else if (k == 1) { atomicAdd(cnt + NA + src, 1.0f);
                               atomicAdd(cnt + 2 * NA + dst, 1.0f); }
            else             atomicAdd(cnt + 3 * NA + src, 1.0f);
        }
    }
    __syncthreads();

    // ---- layer 1: h[64 edges][64] = feat @ W1 ; wave w owns cols 16w..16w+16
    f32x4 acc0 = {0.f,0.f,0.f,0.f}, acc1 = acc0, acc2v = acc0, acc3 = acc0;
#pragma unroll
    for (int kk = 0; kk < 5; kk++) {
        bf16x8 a0 = *(const bf16x8*)&feat[( 0 + m16) * FSTR + kk * 32 + quad * 8];
        bf16x8 a1 = *(const bf16x8*)&feat[(16 + m16) * FSTR + kk * 32 + quad * 8];
        bf16x8 a2 = *(const bf16x8*)&feat[(32 + m16) * FSTR + kk * 32 + quad * 8];
        bf16x8 a3 = *(const bf16x8*)&feat[(48 + m16) * FSTR + kk * 32 + quad * 8];
        acc0 = __builtin_amdgcn_mfma_f32_16x16x32_bf16(a0, b1f[kk], acc0, 0, 0, 0);
        acc1 = __builtin_amdgcn_mfma_f32_16x16x32_bf16(a1, b1f[kk], acc1, 0, 0, 0);
        acc2v = __builtin_amdgcn_mfma_f32_16x16x32_bf16(a2, b1f[kk], acc2v, 0, 0, 0);
        acc3 = __builtin_amdgcn_mfma_f32_16x16x32_bf16(a3, b1f[kk], acc3, 0, 0, 0);
    }

    // ---- layer-2 B fragments: b2f[nt][kk][j] = W2[kk*32+quad*8+j][nt*16+m16]
    bf16x8 b2f[2][2];
    {
        const float* wp = W2 + (size_t)(quad * 8) * DE + m16;
#pragma unroll
        for (int nt = 0; nt < 2; nt++)
#pragma unroll
            for (int kk = 0; kk < 2; kk++)
#pragma unroll
                for (int j = 0; j < 8; j++)
                    b2f[nt][kk][j] = (__bf16)wp[(kk * 32 + j) * DE + nt * 16];
    }

    const float b1c = be1[k * DH + w * 16 + m16];
    __syncthreads();                 // all feat reads done before aliasing
    __bf16* hbuf = feat;             // reuse feat LDS: h [64 edges][64], stride HSTR
    {
        f32x4 av[4] = {acc0, acc1, acc2v, acc3};
#pragma unroll
        for (int mt = 0; mt < 4; mt++)
#pragma unroll
            for (int r = 0; r < 4; r++) {
                float v = av[mt][r] + b1c;
                v = fmaxf(v, 0.f);
                hbuf[(mt * 16 + quad * 4 + r) * HSTR + w * 16 + m16] = (__bf16)v;
            }
    }
    __syncthreads();

    // ---- layer 2: o[64][32] = relu(h) @ W2 ; wave w owns edge rows 16w..16w+16
    f32x4 o0 = {0.f,0.f,0.f,0.f}, o1 = o0;
#pragma unroll
    for (int kk = 0; kk < 2; kk++) {
        bf16x8 a = *(const bf16x8*)&hbuf[(w * 16 + m16) * HSTR + kk * 32 + quad * 8];
        o0 = __builtin_amdgcn_mfma_f32_16x16x32_bf16(a, b2f[0][kk], o0, 0, 0, 0);
        o1 = __builtin_amdgcn_mfma_f32_16x16x32_bf16(a, b2f[1][kk], o1, 0, 0, 0);
    }

    // ---- epilogue: write ne + scatter-aggregate (fp32 atomics, unchanged) ----
    float* sums = ws;
#pragma unroll
    for (int nt = 0; nt < 2; nt++) {
        const int col = nt * 16 + m16;
        const float b2c = be2[k * DE + col];
        const f32x4 oo = nt ? o1 : o0;
#pragma unroll
        for (int r = 0; r < 4; r++) {
            const int er = w * 16 + quad * 4 + r;        // local edge row
            const float v = oo[r] + b2c;
            ne_out[((size_t)k * NEDGE + blk * 64 + er) * DE + col] = v;
            if (k == 0) {
                atomicAdd(&sums[(size_t)sidx[er] * DE + col], v);
            } else if (k == 1) {
                atomicAdd(&sums[WS_SUM + (size_t)sidx[er] * DE + col], v);
                atomicAdd(&sums[(size_t)2 * WS_SUM + (size_t)didx[er] * DE + col], v);
            } else {
                atomicAdd(&sums[(size_t)3 * WS_SUM + (size_t)sidx[er] * DE + col], v);
            }
        }
    }
}

// ---------------- node kernel ----------------
__global__ __launch_bounds__(256, 4) void node_kernel(
    const float* __restrict__ x_a, const float* __restrict__ x_b,
    const float* __restrict__ Wn1, const float* __restrict__ bn1,
    const float* __restrict__ Wn2, const float* __restrict__ bn2,
    float* __restrict__ out,      // nx_a then nx_b, [2*NA][64]
    const float* __restrict__ ws)
{
    __shared__ __bf16 feat[64 * NSTR];   // concat features [64 nodes][128]

    const int tid = threadIdx.x;
    constexpr int BPT = (NA + 63) / 64;  // 1563
    const int t   = blockIdx.x / BPT;    // node type (block-uniform)
    const int blk = blockIdx.x % BPT;

    const float* x = t ? x_b : x_a;
    const float* __restrict__ W1 = Wn1 + (size_t)t * (DN + 2 * DE) * DH;
    const float* __restrict__ W2 = Wn2 + (size_t)t * DH * DN;

    const int w = tid >> 6, lane = tid & 63;
    const int m16 = lane & 15, quad = lane >> 4;

    // ---- layer-1 B fragments in registers: Wn1[kk*32+quad*8+j][w*16+m16]
    bf16x8 b1f[4];
    {
        const float* wp = W1 + (size_t)(quad * 8) * DH + (w * 16 + m16);
#pragma unroll
        for (int kk = 0; kk < 4; kk++)
#pragma unroll
            for (int j = 0; j < 8; j++)
                b1f[kk][j] = (__bf16)wp[(kk * 32 + j) * DH];
    }

    // ---- gather concat features: x | mean1 | mean2 ----
    {
        const int q = tid & 3, nl = tid >> 2;
        const int n = blk * 64 + nl;
        const int ng = (n < NA) ? n : NA - 1;
        const float* cnt = ws + (size_t)4 * WS_SUM;
        const float inv1 = 1.0f / fmaxf(cnt[(size_t)(2 * t) * NA + ng], 1.0f);
        const float inv2 = 1.0f / fmaxf(cnt[(size_t)(2 * t + 1) * NA + ng], 1.0f);

        const float4* px = (const float4*)(x + (size_t)ng * DN);
        const float4* p1 = (const float4*)(ws + (size_t)(2 * t) * WS_SUM + (size_t)ng * DE);
        const float4* p2 = (const float4*)(ws + (size_t)(2 * t + 1) * WS_SUM + (size_t)ng * DE);
#pragma unroll
        for (int i = 0; i < 4; i++) {
            float4 v = px[q * 4 + i];
            bf16x4 tt = {(__bf16)v.x, (__bf16)v.y, (__bf16)v.z, (__bf16)v.w};
            *(bf16x4*)&feat[nl * NSTR + q * 16 + i * 4] = tt;
        }
#pragma unroll
        for (int i = 0; i < 2; i++) {
            float4 v = p1[q * 2 + i];
            bf16x4 tt = {(__bf16)(v.x * inv1), (__bf16)(v.y * inv1),
                         (__bf16)(v.z * inv1), (__bf16)(v.w * inv1)};
            *(bf16x4*)&feat[nl * NSTR + 64 + q * 8 + i * 4] = tt;
        }
#pragma unroll
        for (int i = 0; i < 2; i++) {
            float4 v = p2[q * 2 + i];
            bf16x4 tt = {(__bf16)(v.x * inv2), (__bf16)(v.y * inv2),
                         (__bf16)(v.z * inv2), (__bf16)(v.w * inv2)};
            *(bf16x4*)&feat[nl * NSTR + 96 + q * 8 + i * 4] = tt;
        }
    }
    __syncthreads();

    // ---- layer 1: h = feat[64][128] @ Wn1 ; wave w owns cols 16w..16w+16
    f32x4 acc0 = {0.f,0.f,0.f,0.f}, acc1 = acc0, acc2v = acc0, acc3 = acc0;
#pragma unroll
    for (int kk = 0; kk < 4; kk++) {
        bf16x8 a0 = *(const bf16x8*)&feat[( 0 + m16) * NSTR + kk * 32 + quad * 8];
        bf16x8 a1 = *(const bf16x8*)&feat[(16 + m16) * NSTR + kk * 32 + quad * 8];
        bf16x8 a2 = *(const bf16x8*)&feat[(32 + m16) * NSTR + kk * 32 + quad * 8];
        bf16x8 a3 = *(const bf16x8*)&feat[(48 + m16) * NSTR + kk * 32 + quad * 8];
        acc0 = __builtin_amdgcn_mfma_f32_16x16x32_bf16(a0, b1f[kk], acc0, 0, 0, 0);
        acc1 = __builtin_amdgcn_mfma_f32_16x16x32_bf16(a1, b1f[kk], acc1, 0, 0, 0);
        acc2v = __builtin_amdgcn_mfma_f32_16x16x32_bf16(a2, b1f[kk], acc2v, 0, 0, 0);
        acc3 = __builtin_amdgcn_mfma_f32_16x16x32_bf16(a3, b1f[kk], acc3, 0, 0, 0);
    }

    // ---- layer-2 B fragments: Wn2[kk*32+quad*8+j][nt*16+m16]
    bf16x8 b2f[4][2];
    {
        const float* wp = W2 + (size_t)(quad * 8) * DN + m16;
#pragma unroll
        for (int nt = 0; nt < 4; nt++)
#pragma unroll
            for (int kk = 0; kk < 2; kk++)
#pragma unroll
                for (int j = 0; j < 8; j++)
                    b2f[nt][kk][j] = (__bf16)wp[(kk * 32 + j) * DN + nt * 16];
    }

    const float b1c = bn1[t * DH + w * 16 + m16];
    __syncthreads();
    __bf16* hbuf = feat;             // alias, h [64 nodes][64], stride HSTR
    {
        f32x4 av[4] = {acc0, acc1, acc2v, acc3};
#pragma unroll
        for (int mt = 0; mt < 4; mt++)
#pragma unroll
            for (int r = 0; r < 4; r++) {
                float v = av[mt][r] + b1c;
                v = fmaxf(v, 0.f);
                hbuf[(mt * 16 + quad * 4 + r) * HSTR + w * 16 + m16] = (__bf16)v;
            }
    }
    __syncthreads();

    // ---- layer 2: nx[64][64] = relu(h) @ Wn2 ; wave w owns node rows 16w..
    f32x4 o0 = {0.f,0.f,0.f,0.f}, o1 = o0, o2 = o0, o3 = o0;
#pragma unroll
    for (int kk = 0; kk < 2; kk++) {
        bf16x8 a = *(const bf16x8*)&hbuf[(w * 16 + m16) * HSTR + kk * 32 + quad * 8];
        o0 = __builtin_amdgcn_mfma_f32_16x16x32_bf16(a, b2f[0][kk], o0, 0, 0, 0);
        o1 = __builtin_amdgcn_mfma_f32_16x16x32_bf16(a, b2f[1][kk], o1, 0, 0, 0);
        o2 = __builtin_amdgcn_mfma_f32_16x16x32_bf16(a, b2f[2][kk], o2, 0, 0, 0);
        o3 = __builtin_amdgcn_mfma_f32_16x16x32_bf16(a, b2f[3][kk], o3, 0, 0, 0);
    }
#pragma unroll
    for (int nt = 0; nt < 4; nt++) {
        const int col = nt * 16 + m16;
        const float b2c = bn2[t * DN + col];
        const f32x4 oo = (nt == 0) ? o0 : (nt == 1) ? o1 : (nt == 2) ? o2 : o3;
#pragma unroll
        for (int r = 0; r < 4; r++) {
            const int n = blk * 64 + w * 16 + quad * 4 + r;
            if (n < NA)
                out[((size_t)t * NA + n) * DN + col] = oo[r] + b2c;
        }
    }
}

extern "C" void kernel_launch(void* const* d_in, const int* in_sizes, int n_in,
                              void* d_out, int out_size, void* d_ws, size_t ws_size,
                              hipStream_t stream)
{
    const float* x_a  = (const float*)d_in[0];
    const float* x_b  = (const float*)d_in[1];
    const int*   ei_aa = (const int*)d_in[2];
    const int*   ei_ab = (const int*)d_in[3];
    const int*   ei_bb = (const int*)d_in[4];
    const float* ea_aa = (const float*)d_in[5];
    const float* ea_ab = (const float*)d_in[6];
    const float* ea_bb = (const float*)d_in[7];
    const float* We1 = (const float*)d_in[8];
    const float* be1 = (const float*)d_in[9];
    const float* We2 = (const float*)d_in[10];
    const float* be2 = (const float*)d_in[11];
    const float* Wn1 = (const float*)d_in[12];
    const float* bn1 = (const float*)d_in[13];
    const float* Wn2 = (const float*)d_in[14];
    const float* bn2 = (const float*)d_in[15];

    float* out = (float*)d_out;
    float* ws  = (float*)d_ws;

    zero_ws<<<1024, 256, 0, stream>>>((float4*)ws, WS_FLOATS / 4);

    constexpr int BPT_E = NEDGE / 64;        // 6250
    edge_kernel<<<3 * BPT_E, 256, 0, stream>>>(
        x_a, x_b, ei_aa, ei_ab, ei_bb, ea_aa, ea_ab, ea_bb,
        We1, be1, We2, be2, out + (size_t)2 * NA * DN, ws);

    constexpr int BPT_N = (NA + 63) / 64;    // 1563
    node_kernel<<<2 * BPT_N, 256, 0, stream>>>(
        x_a, x_b, Wn1, bn1, Wn2, bn2, out, ws);
}